// Round 8
// baseline (3401.300 us; speedup 1.0000x reference)
//
#include <hip/hip_runtime.h>
#include <hip/hip_bf16.h>

// ESN recurrence, B=16 T=512 F=512 H=2048 V=64.
// Batch-staggered systolic design: WG = 8 rows x all batches (256 WGs x 128
// thr). Wave = 8 rows x 8 K-slices; wave0 sweeps even batches, wave1 odd,
// sequentially within each step. h_t[b] is published ~1 full step before its
// consumers reach batch b, so L3 latency/jitter is absorbed by pipeline slack:
// no barriers, no steady-state spinning. Exchange: tagged 8B {8-row nibbles,
// tag} units, replicated x8 to spread hot-line read pressure (R6/R7 lesson).
// Input-dot precomputed exactly (int clamp + f32 scale) by a parallel GEMM.
// Integer math exact (v_dot8_i32_i4); FP path replicates XLA/Eigen f32 tanh.
// Workspace requirement: ~104 MiB.

#define B_ 16
#define T_ 512
#define F_ 512
#define H_ 2048
#define V_ 64
#define NWG 256
#define NTHREADS 128
#define REP 8  // exchange replicas

typedef unsigned long long ull;

#if defined(__has_builtin)
#if __has_builtin(__builtin_amdgcn_sdot8)
#define HAVE_SDOT8 1
#endif
#endif

__device__ __forceinline__ int sdot8(int a, int b, int c) {
#ifdef HAVE_SDOT8
  return __builtin_amdgcn_sdot8(a, b, c, false);
#else
#pragma unroll
  for (int i = 0; i < 8; ++i) {
    int av = (a << (28 - 4 * i)) >> 28;
    int bv = (b << (28 - 4 * i)) >> 28;
    c += av * bv;
  }
  return c;
#endif
}

// XLA / Eigen generic_fast_tanh_float, f32, fma form (bit-matching matters:
// quantized recurrence is chaotic at ULP level).
__device__ __forceinline__ float tanh_ref(float x) {
  float ax = fabsf(x);
  float xc = fminf(fmaxf(x, -7.90531110763549805f), 7.90531110763549805f);
  float x2 = __fmul_rn(xc, xc);
  float p = -2.76076847742355e-16f;
  p = __fmaf_rn(x2, p, 2.00018790482477e-13f);
  p = __fmaf_rn(x2, p, -8.60467152213735e-11f);
  p = __fmaf_rn(x2, p, 5.12229709037114e-08f);
  p = __fmaf_rn(x2, p, 1.48572235717979e-05f);
  p = __fmaf_rn(x2, p, 6.37261928875436e-04f);
  p = __fmaf_rn(x2, p, 4.89352455891786e-03f);
  p = __fmul_rn(xc, p);
  float q = 1.19825839466702e-06f;
  q = __fmaf_rn(x2, q, 1.18534705686654e-04f);
  q = __fmaf_rn(x2, q, 2.26843463243900e-03f);
  q = __fmaf_rn(x2, q, 4.89352518554385e-03f);
  float r = __fdiv_rn(p, q);
  return (ax < 0.0004f) ? x : r;
}

__device__ __forceinline__ unsigned f2bf(float f) {  // f32 -> bf16 bits, RNE
  unsigned u = __float_as_uint(f);
  return (u + 0x7fffu + ((u >> 16) & 1u)) >> 16;
}

__device__ __forceinline__ ull xld(const ull* p) {
  return __hip_atomic_load(p, __ATOMIC_RELAXED, __HIP_MEMORY_SCOPE_AGENT);
}
__device__ __forceinline__ void xst(ull* p, ull v) {
  __hip_atomic_store(p, v, __ATOMIC_RELAXED, __HIP_MEMORY_SCOPE_AGENT);
}

// ---- prep: pack weights to int4 nibbles ------------------------------------
__global__ void pack_weights(const int* __restrict__ Wres, const int* __restrict__ Win,
                             int* __restrict__ wr4, int* __restrict__ wi4) {
  int id = blockIdx.x * blockDim.x + threadIdx.x;
  if (id < H_ * 256) {
    const int* src = Wres + id * 8;
    int pk = 0;
#pragma unroll
    for (int i = 0; i < 8; ++i) pk |= (src[i] & 15) << (4 * i);
    wr4[id] = pk;
  } else {
    int id2 = id - H_ * 256;
    if (id2 < H_ * 64) {
      const int* src = Win + id2 * 8;
      int pk = 0;
#pragma unroll
      for (int i = 0; i < 8; ++i) pk |= (src[i] & 15) << (4 * i);
      wi4[id2] = pk;
    }
  }
}

// ---- prep: quantize input, split u = 8*a + m into two int4 planes ----------
__global__ void pack_u(const float* __restrict__ x, int* __restrict__ um, int* __restrict__ ua) {
  int idx = blockIdx.x * blockDim.x + threadIdx.x;
  if (idx >= B_ * T_ * 64) return;
  const float* src = x + (size_t)idx * 8;
  int pm = 0, pa = 0;
#pragma unroll
  for (int i = 0; i < 8; ++i) {
    int u = (int)rintf(__fmul_rn(src[i], 3.0f));  // round-half-even == jnp.round
    int vv = u + 128;
    pm |= (vv & 7) << (4 * i);
    pa |= (((vv >> 3) - 16) & 15) << (4 * i);
  }
  um[idx] = pm;
  ua[idx] = pa;
}

// ---- prep: exact input-dot precompute --------------------------------------
// fin[bt*H + row] = (float)clamp_i16(am + (aa<<3)) * (S_in[row]/21*g_in)
// Bit-identical to doing it in the recurrence loop (integer sums exact; the
// f32 product is the exact reference value out_in_f * s_in).
__global__ void __launch_bounds__(256) input_gemm(
    const int* __restrict__ um, const int* __restrict__ ua, const int* __restrict__ wi4,
    const float* __restrict__ S_in, const float* __restrict__ g_in, float* __restrict__ fin) {
  __shared__ int su[1024];  // 8 bt x (64 um | 64 ua) dwords
  const int btg = blockIdx.x;                       // group of 8 bt
  const int row = blockIdx.y * 256 + threadIdx.x;
  for (int k = threadIdx.x; k < 1024; k += 256) {
    int bt = k >> 7, c = k & 127;
    su[k] = (c < 64) ? um[(btg * 8 + bt) * 64 + c] : ua[(btg * 8 + bt) * 64 + (c - 64)];
  }
  __syncthreads();
  ::int4 w[16];
  const ::int4* gw = (const ::int4*)wi4;
#pragma unroll
  for (int i = 0; i < 16; ++i) w[i] = gw[row * 16 + i];
  const float si = __fmul_rn(__fdiv_rn(S_in[row], 21.0f), g_in[0]);
#pragma unroll
  for (int g = 0; g < 8; ++g) {
    const ::int4* uM = (const ::int4*)(su + g * 128);
    const ::int4* uA = (const ::int4*)(su + g * 128 + 64);
    int am = 0, aa = 0;
#pragma unroll
    for (int i = 0; i < 16; ++i) {
      ::int4 wi = w[i]; ::int4 m = uM[i]; ::int4 a = uA[i];
      am = sdot8(wi.x, m.x, am); am = sdot8(wi.y, m.y, am);
      am = sdot8(wi.z, m.z, am); am = sdot8(wi.w, m.w, am);
      aa = sdot8(wi.x, a.x, aa); aa = sdot8(wi.y, a.y, aa);
      aa = sdot8(wi.z, a.z, aa); aa = sdot8(wi.w, a.w, aa);
    }
    int acc = am + (aa << 3);
    acc = min(max(acc, -32768), 32767);
    fin[(size_t)(btg * 8 + g) * H_ + row] = __fmul_rn((float)acc, si);
  }
}

// ---- main persistent kernel ------------------------------------------------
// WG w owns rows [w*8,+8). Wave wv sweeps batches {wv, wv+2, ...}. Lane =
// (row r = lane>>3, K-slice kq = lane&7). Substep s: t = s>>3, b = 2*(s&7)|wv.
// h exchange: unit = {data32 = 8 rows' nibbles, tag32 = t}, 256 units/batch,
// replicated x8; consumer reads replica wg&7. Prefetch depth 4 (registers),
// tag-checked at use. Per-wave private LDS staging (stride-20, b128-aligned).
__global__ void __launch_bounds__(NTHREADS, 1) esn_main(
    const int* __restrict__ wr4, ull* hq,
    const float* __restrict__ S_res, const float* __restrict__ g_res,
    const float* __restrict__ fin, unsigned* __restrict__ Hs, int t0, int t1) {
  __shared__ int lds_h[2][320];
  const int wg = blockIdx.x;
  const int tid = threadIdx.x;
  const int wv = tid >> 6;        // batch class
  const int lane = tid & 63;
  const int r = lane >> 3, kq = lane & 7;
  const int grow = wg * 8 + r;
  const size_t cpy = (size_t)(wg & (REP - 1));
  int* hb = lds_h[wv];
  const int wofs = (lane >> 2) * 20 + (lane & 3) * 4;  // staging write offset
  int* hrd = hb + 40 * kq;                             // dot read base

  ::int4 wreg[8];
  {
    const ::int4* gw = (const ::int4*)wr4;  // row-major, 64 int4/row
#pragma unroll
    for (int j = 0; j < 8; ++j) wreg[j] = gw[grow * 64 + kq * 8 + j];
  }
  const float sr = __fmul_rn(__fdiv_rn(S_res[grow], 49.0f), g_res[0]);

  const int sBeg = t0 * 8, sEnd = t1 * 8;

#define PRE(P, sarg)                                                                     \
  {                                                                                      \
    int sc_ = (sarg);                                                                    \
    if (sc_ > sEnd - 1) sc_ = sEnd - 1;                                                  \
    const int tt_ = sc_ >> 3, bb_ = ((sc_ & 7) << 1) | wv;                               \
    const ull* pp_ = hq + (((cpy << 5) + ((size_t)(tt_ & 1) << 4) + bb_) << 8) + (lane << 2); \
    P##a = xld(pp_); P##b = xld(pp_ + 1); P##c = xld(pp_ + 2); P##d = xld(pp_ + 3);      \
    P##f = fin[((((size_t)bb_ << 9) + tt_) << 11) + grow];                               \
  }

#define CONS(P, sarg)                                                                    \
  {                                                                                      \
    const int s_ = (sarg);                                                               \
    const int tt = s_ >> 3;                                                              \
    const int bb = ((s_ & 7) << 1) | wv;                                                 \
    const unsigned tg = (unsigned)tt;                                                    \
    const ull* pp = hq + (((cpy << 5) + ((size_t)(tt & 1) << 4) + bb) << 8) + (lane << 2); \
    while ((((unsigned)(P##a >> 32)) ^ tg) | (((unsigned)(P##b >> 32)) ^ tg) |           \
           (((unsigned)(P##c >> 32)) ^ tg) | (((unsigned)(P##d >> 32)) ^ tg)) {          \
      P##a = xld(pp); P##b = xld(pp + 1); P##c = xld(pp + 2); P##d = xld(pp + 3);        \
    }                                                                                    \
    ::int4 hv_;                                                                          \
    hv_.x = (int)P##a; hv_.y = (int)P##b; hv_.z = (int)P##c; hv_.w = (int)P##d;          \
    const float finv = P##f;                                                             \
    PRE(P, s_ + 4);                                                                      \
    *(::int4*)(hb + wofs) = hv_;                                                         \
    __builtin_amdgcn_sched_barrier(0);                                                   \
    int c0 = 0, c1 = 0, c2 = 0, c3 = 0;                                                  \
    {                                                                                    \
      ::int4 h0 = *(const ::int4*)(hrd + 0);  ::int4 h1 = *(const ::int4*)(hrd + 4);     \
      ::int4 h2 = *(const ::int4*)(hrd + 8);  ::int4 h3 = *(const ::int4*)(hrd + 12);    \
      ::int4 h4 = *(const ::int4*)(hrd + 20); ::int4 h5 = *(const ::int4*)(hrd + 24);    \
      ::int4 h6 = *(const ::int4*)(hrd + 28); ::int4 h7 = *(const ::int4*)(hrd + 32);    \
      c0 = sdot8(wreg[0].x, h0.x, c0); c0 = sdot8(wreg[0].y, h0.y, c0);                  \
      c0 = sdot8(wreg[0].z, h0.z, c0); c0 = sdot8(wreg[0].w, h0.w, c0);                  \
      c1 = sdot8(wreg[1].x, h1.x, c1); c1 = sdot8(wreg[1].y, h1.y, c1);                  \
      c1 = sdot8(wreg[1].z, h1.z, c1); c1 = sdot8(wreg[1].w, h1.w, c1);                  \
      c2 = sdot8(wreg[2].x, h2.x, c2); c2 = sdot8(wreg[2].y, h2.y, c2);                  \
      c2 = sdot8(wreg[2].z, h2.z, c2); c2 = sdot8(wreg[2].w, h2.w, c2);                  \
      c3 = sdot8(wreg[3].x, h3.x, c3); c3 = sdot8(wreg[3].y, h3.y, c3);                  \
      c3 = sdot8(wreg[3].z, h3.z, c3); c3 = sdot8(wreg[3].w, h3.w, c3);                  \
      c0 = sdot8(wreg[4].x, h4.x, c0); c0 = sdot8(wreg[4].y, h4.y, c0);                  \
      c0 = sdot8(wreg[4].z, h4.z, c0); c0 = sdot8(wreg[4].w, h4.w, c0);                  \
      c1 = sdot8(wreg[5].x, h5.x, c1); c1 = sdot8(wreg[5].y, h5.y, c1);                  \
      c1 = sdot8(wreg[5].z, h5.z, c1); c1 = sdot8(wreg[5].w, h5.w, c1);                  \
      c2 = sdot8(wreg[6].x, h6.x, c2); c2 = sdot8(wreg[6].y, h6.y, c2);                  \
      c2 = sdot8(wreg[6].z, h6.z, c2); c2 = sdot8(wreg[6].w, h6.w, c2);                  \
      c3 = sdot8(wreg[7].x, h7.x, c3); c3 = sdot8(wreg[7].y, h7.y, c3);                  \
      c3 = sdot8(wreg[7].z, h7.z, c3); c3 = sdot8(wreg[7].w, h7.w, c3);                  \
    }                                                                                    \
    int acc = (c0 + c1) + (c2 + c3);                                                     \
    acc += __shfl_xor(acc, 1);                                                           \
    acc += __shfl_xor(acc, 2);                                                           \
    acc += __shfl_xor(acc, 4);                                                           \
    int cr = min(max(acc, -32768), 32767);                                               \
    float arg = __fadd_rn(__fmul_rn((float)cr, sr), finv);                               \
    float hn = tanh_ref(arg);                                                            \
    float hc = fminf(fmaxf(hn, -1.0f), 1.0f);                                            \
    int qv = (int)rintf(__fmul_rn(hc, 7.0f));                                            \
    unsigned nib = ((unsigned)qv & 15u) << (4 * r);                                      \
    nib |= (unsigned)__shfl_xor((int)nib, 8);                                            \
    nib |= (unsigned)__shfl_xor((int)nib, 16);                                           \
    nib |= (unsigned)__shfl_xor((int)nib, 32);                                           \
    if (lane == 0) {                                                                     \
      ull uv = ((ull)(unsigned)(tt + 1) << 32) | nib;                                    \
      ull* pb = hq + ((((size_t)((tt + 1) & 1) << 4) + bb) << 8) + wg;                   \
      _Pragma("unroll")                                                                  \
      for (int c_ = 0; c_ < REP; ++c_) xst(pb + ((size_t)c_ << 13), uv);                 \
    }                                                                                    \
    unsigned bfb = f2bf(hn);                                                             \
    unsigned oth = (unsigned)__shfl_xor((int)bfb, 8);                                    \
    if ((lane & 15) == 0)                                                                \
      Hs[((((size_t)bb << 9) + tt) << 10) + wg * 4 + (lane >> 4)] = bfb | (oth << 16);   \
  }

  ull p0a, p0b, p0c, p0d; float p0f;
  ull p1a, p1b, p1c, p1d; float p1f;
  ull p2a, p2b, p2c, p2d; float p2f;
  ull p3a, p3b, p3c, p3d; float p3f;
  PRE(p0, sBeg)
  PRE(p1, sBeg + 1)
  PRE(p2, sBeg + 2)
  PRE(p3, sBeg + 3)
  for (int s = sBeg; s < sEnd; s += 4) {
    CONS(p0, s)
    CONS(p1, s + 1)
    CONS(p2, s + 2)
    CONS(p3, s + 3)
  }
#undef PRE
#undef CONS
}

// ---- deferred readout: 512 blocks x 256 thr; 16 bt-rows x 64 v per block ---
#define ACC8(acc, p, w0, w1)                                    \
  acc = fmaf(__uint_as_float(p.x << 16), w0.x, acc);            \
  acc = fmaf(__uint_as_float(p.x & 0xffff0000u), w0.y, acc);    \
  acc = fmaf(__uint_as_float(p.y << 16), w0.z, acc);            \
  acc = fmaf(__uint_as_float(p.y & 0xffff0000u), w0.w, acc);    \
  acc = fmaf(__uint_as_float(p.z << 16), w1.x, acc);            \
  acc = fmaf(__uint_as_float(p.z & 0xffff0000u), w1.y, acc);    \
  acc = fmaf(__uint_as_float(p.w << 16), w1.z, acc);            \
  acc = fmaf(__uint_as_float(p.w & 0xffff0000u), w1.w, acc);

__global__ void __launch_bounds__(256) readout(const unsigned* __restrict__ Hs,
                                               const float* __restrict__ Wout,
                                               const float* __restrict__ Wb,
                                               float* __restrict__ out) {
  const int v = threadIdx.x & 63;
  const int rg = threadIdx.x >> 6;
  const int bt0 = blockIdx.x * 16 + rg * 4;
  const float* wrow = Wout + (size_t)v * H_;
  const unsigned* h0 = Hs + (size_t)bt0 * (H_ / 2);
  float a0 = Wb[v], a1 = a0, a2 = a0, a3 = a0;
  for (int j = 0; j < H_ / 2; j += 4) {
    float4 w0 = *(const float4*)(wrow + 2 * j);
    float4 w1 = *(const float4*)(wrow + 2 * j + 4);
    uint4 p0 = *(const uint4*)(h0 + j);
    uint4 p1 = *(const uint4*)(h0 + (H_ / 2) + j);
    uint4 p2 = *(const uint4*)(h0 + 2 * (H_ / 2) + j);
    uint4 p3 = *(const uint4*)(h0 + 3 * (H_ / 2) + j);
    ACC8(a0, p0, w0, w1)
    ACC8(a1, p1, w0, w1)
    ACC8(a2, p2, w0, w1)
    ACC8(a3, p3, w0, w1)
  }
  out[(size_t)(bt0 + 0) * V_ + v] = a0;
  out[(size_t)(bt0 + 1) * V_ + v] = a1;
  out[(size_t)(bt0 + 2) * V_ + v] = a2;
  out[(size_t)(bt0 + 3) * V_ + v] = a3;
}

extern "C" void kernel_launch(void* const* d_in, const int* in_sizes, int n_in,
                              void* d_out, int out_size, void* d_ws, size_t ws_size,
                              hipStream_t stream) {
  const float* x = (const float*)d_in[0];
  const float* S_res = (const float*)d_in[1];
  const float* S_in = (const float*)d_in[2];
  const float* g_res = (const float*)d_in[3];
  const float* g_in = (const float*)d_in[4];
  const float* Woutw = (const float*)d_in[5];
  const float* Woutb = (const float*)d_in[6];
  const int* Wres = (const int*)d_in[7];
  const int* Win = (const int*)d_in[8];

  char* ws = (char*)d_ws;
  ull* hq = (ull*)ws;                                  // 512 KiB (8 replicas)
  int* wr4 = (int*)(ws + (1 << 20));                   // 2 MiB
  int* wi4 = (int*)(ws + (3 << 20));                   // 512 KiB
  int* um = (int*)(ws + ((size_t)4 << 20));            // 2 MiB
  int* ua = (int*)(ws + ((size_t)6 << 20));            // 2 MiB
  unsigned* Hs = (unsigned*)(ws + ((size_t)8 << 20));  // 32 MiB
  float* fin = (float*)(ws + ((size_t)40 << 20));      // 64 MiB
  // total requirement ~104 MiB

  hipMemsetAsync(hq, 0, (size_t)REP * 32 * 256 * 8, stream);  // h0 = 0, tag0 = 0
  hipLaunchKernelGGL(pack_weights, dim3(2560), dim3(256), 0, stream, Wres, Win, wr4, wi4);
  hipLaunchKernelGGL(pack_u, dim3(2048), dim3(256), 0, stream, x, um, ua);
  hipLaunchKernelGGL(input_gemm, dim3(B_ * T_ / 8, 8), dim3(256), 0, stream,
                     um, ua, wi4, S_in, g_in, fin);

  int t0 = 0, t1 = T_;
  void* args[] = {&wr4, &hq, &S_res, &g_res, &fin, &Hs, &t0, &t1};
  hipError_t e = hipLaunchCooperativeKernel((const void*)esn_main, dim3(NWG), dim3(NTHREADS),
                                            args, 0, stream);
  if (e != hipSuccess) {
    // fallback: one launch per timestep (kernel boundary = sync)
    for (int t = 0; t < T_; ++t) {
      hipLaunchKernelGGL(esn_main, dim3(NWG), dim3(NTHREADS), 0, stream,
                         wr4, hq, S_res, g_res, fin, Hs, t, t + 1);
    }
  }
  hipLaunchKernelGGL(readout, dim3(B_ * T_ / 16), dim3(256), 0, stream,
                     Hs, Woutw, Woutb, (float*)d_out);
}

// Round 9
// 1946.320 us; speedup vs baseline: 1.7476x; 1.7476x over previous
//
#include <hip/hip_runtime.h>
#include <hip/hip_bf16.h>

// ESN recurrence, B=16 T=512 F=512 H=2048 V=64.
// Integer matvecs exact (int4 packed, v_dot8_i32_i4). FP path replicates
// XLA/Eigen f32 tanh. 32 slice-WGs per batch exchange h as tagged 8B
// {data,tag} units via relaxed agent-scope atomics. R9: barrier-free loop —
// every thread polls ONE unit; each wave stages its K-quarter to LDS and
// sets an LDS flag (workgroup release/acquire); the dot consumes 4 int4 per
// arrival-quarter (flag-gated), so early quarters' compute overlaps the last
// quarter's L3 latency. Weight slice in LDS, prefetched to regs each step
// via anchored volatile-asm ds_read_b128 draining during the poll window.

#define B_ 16
#define T_ 512
#define F_ 512
#define H_ 2048
#define V_ 64
#define SLICES 32
#define RPW 64       // rows per workgroup
#define NTHREADS 256
#define NWG 512      // 16 batches x 32 slices

typedef int i4v __attribute__((ext_vector_type(4)));
typedef unsigned long long ull;

#if defined(__has_builtin)
#if __has_builtin(__builtin_amdgcn_sdot8)
#define HAVE_SDOT8 1
#endif
#endif

__device__ __forceinline__ int sdot8(int a, int b, int c) {
#ifdef HAVE_SDOT8
  return __builtin_amdgcn_sdot8(a, b, c, false);
#else
#pragma unroll
  for (int i = 0; i < 8; ++i) {
    int av = (a << (28 - 4 * i)) >> 28;
    int bv = (b << (28 - 4 * i)) >> 28;
    c += av * bv;
  }
  return c;
#endif
}

// XLA / Eigen generic_fast_tanh_float, f32, fma form (bit-matching matters:
// quantized recurrence is chaotic at ULP level).
__device__ __forceinline__ float tanh_ref(float x) {
  float ax = fabsf(x);
  float xc = fminf(fmaxf(x, -7.90531110763549805f), 7.90531110763549805f);
  float x2 = __fmul_rn(xc, xc);
  float p = -2.76076847742355e-16f;
  p = __fmaf_rn(x2, p, 2.00018790482477e-13f);
  p = __fmaf_rn(x2, p, -8.60467152213735e-11f);
  p = __fmaf_rn(x2, p, 5.12229709037114e-08f);
  p = __fmaf_rn(x2, p, 1.48572235717979e-05f);
  p = __fmaf_rn(x2, p, 6.37261928875436e-04f);
  p = __fmaf_rn(x2, p, 4.89352455891786e-03f);
  p = __fmul_rn(xc, p);
  float q = 1.19825839466702e-06f;
  q = __fmaf_rn(x2, q, 1.18534705686654e-04f);
  q = __fmaf_rn(x2, q, 2.26843463243900e-03f);
  q = __fmaf_rn(x2, q, 4.89352518554385e-03f);
  float r = __fdiv_rn(p, q);
  return (ax < 0.0004f) ? x : r;
}

__device__ __forceinline__ unsigned f2bf(float f) {  // f32 -> bf16 bits, RNE
  unsigned u = __float_as_uint(f);
  return (u + 0x7fffu + ((u >> 16) & 1u)) >> 16;
}

__device__ __forceinline__ ull xld(const ull* p) {
  return __hip_atomic_load(p, __ATOMIC_RELAXED, __HIP_MEMORY_SCOPE_AGENT);
}
__device__ __forceinline__ void publish_tag(ull* p, unsigned data, unsigned tag) {
  ull u = ((ull)tag << 32) | data;
  __hip_atomic_store(p, u, __ATOMIC_RELAXED, __HIP_MEMORY_SCOPE_AGENT);
}

// ---- prep: pack weights to int4 nibbles ------------------------------------
__global__ void pack_weights(const int* __restrict__ Wres, const int* __restrict__ Win,
                             int* __restrict__ wr4, int* __restrict__ wi4) {
  int id = blockIdx.x * blockDim.x + threadIdx.x;
  if (id < H_ * 256) {
    const int* src = Wres + id * 8;
    int pk = 0;
#pragma unroll
    for (int i = 0; i < 8; ++i) pk |= (src[i] & 15) << (4 * i);
    wr4[id] = pk;
  } else {
    int id2 = id - H_ * 256;
    if (id2 < H_ * 64) {
      const int* src = Win + id2 * 8;
      int pk = 0;
#pragma unroll
      for (int i = 0; i < 8; ++i) pk |= (src[i] & 15) << (4 * i);
      wi4[id2] = pk;
    }
  }
}

// ---- prep: quantize input, split u = 8*a + m into two int4 planes ----------
__global__ void pack_u(const float* __restrict__ x, int* __restrict__ um, int* __restrict__ ua) {
  int idx = blockIdx.x * blockDim.x + threadIdx.x;
  if (idx >= B_ * T_ * 64) return;
  const float* src = x + (size_t)idx * 8;
  int pm = 0, pa = 0;
#pragma unroll
  for (int i = 0; i < 8; ++i) {
    int u = (int)rintf(__fmul_rn(src[i], 3.0f));  // round-half-even == jnp.round
    int vv = u + 128;
    pm |= (vv & 7) << (4 * i);
    pa |= (((vv >> 3) - 16) & 15) << (4 * i);
  }
  um[idx] = pm;
  ua[idx] = pa;
}

// anchored weight reads: issued pre-poll, drain during the observe window
#define WLD(i, OFFSTR) \
  asm volatile("ds_read_b128 %0, %1 offset:" OFFSTR : "=v"(wreg[i]) : "v"(lds_wb))

// one arrival-quarter partial dot (flag-gated)
#define QDOT(QQ)                                                                     \
  {                                                                                  \
    while (__hip_atomic_load(&lds_flag[cbuf * 4 + QQ], __ATOMIC_ACQUIRE,             \
                             __HIP_MEMORY_SCOPE_WORKGROUP) < t) {}                   \
    const ::int4* h4 = (const ::int4*)hbase + QQ * 17 + q * 4;                       \
    ::int4 h0 = h4[0], h1 = h4[1], h2 = h4[2], h3 = h4[3];                           \
    c0 = sdot8(wreg[QQ * 4 + 0].x, h0.x, c0); c0 = sdot8(wreg[QQ * 4 + 0].y, h0.y, c0); \
    c0 = sdot8(wreg[QQ * 4 + 0].z, h0.z, c0); c0 = sdot8(wreg[QQ * 4 + 0].w, h0.w, c0); \
    c1 = sdot8(wreg[QQ * 4 + 1].x, h1.x, c1); c1 = sdot8(wreg[QQ * 4 + 1].y, h1.y, c1); \
    c1 = sdot8(wreg[QQ * 4 + 1].z, h1.z, c1); c1 = sdot8(wreg[QQ * 4 + 1].w, h1.w, c1); \
    c2 = sdot8(wreg[QQ * 4 + 2].x, h2.x, c2); c2 = sdot8(wreg[QQ * 4 + 2].y, h2.y, c2); \
    c2 = sdot8(wreg[QQ * 4 + 2].z, h2.z, c2); c2 = sdot8(wreg[QQ * 4 + 2].w, h2.w, c2); \
    c3 = sdot8(wreg[QQ * 4 + 3].x, h3.x, c3); c3 = sdot8(wreg[QQ * 4 + 3].y, h3.y, c3); \
    c3 = sdot8(wreg[QQ * 4 + 3].z, h3.z, c3); c3 = sdot8(wreg[QQ * 4 + 3].w, h3.w, c3); \
  }

// ---- main persistent kernel ------------------------------------------------
// WG = (batch b = wg&15, slice = wg>>4). Thread = (row tid>>2, K-quarter
// q=tid&3). Wave wv owns rows [slice*64+wv*16,+16) and arrival-quarter wv.
__global__ void __launch_bounds__(NTHREADS, 2) esn_main(
    const int* __restrict__ um, const int* __restrict__ ua,
    const int* __restrict__ wr4, const int* __restrict__ wi4,
    ull* hq,
    const float* __restrict__ S_res, const float* __restrict__ S_in,
    const float* __restrict__ g_res, const float* __restrict__ g_in,
    unsigned* __restrict__ Hs, int t0, int t1) {
  extern __shared__ __align__(16) char smem[];
  ::int4* lw4 = (::int4*)smem;                 // 16*256 int4 = 64 KiB
  int* lds_h = (int*)(lw4 + 16 * 256);         // 2 * 272 dw (17-int4 quarter stride)
  int* lds_u = lds_h + 2 * 272;                // 2 * 128 dw
  int* lds_flag = lds_u + 2 * 128;             // 2 * 4 ints

  const int wg = blockIdx.x;
  const int b = wg & 15, slice = wg >> 4;
  const int tid = threadIdx.x;
  const int wv = tid >> 6;
  const int lane = tid & 63;
  const int q = tid & 3;
  const int grow = slice * RPW + (tid >> 2);

  // one-time: W_res slice -> LDS, transposed; thread's j-th int4 covers
  // arrival-quarter j>>2, sub-block j&3 of its K-quarter q.
  {
    const ::int4* gw = (const ::int4*)wr4;  // 64 int4 per row
#pragma unroll 4
    for (int j = 0; j < 16; ++j)
      lw4[j * 256 + tid] = gw[grow * 64 + (j >> 2) * 16 + q * 4 + (j & 3)];
  }
  // W_in quarter -> regs
  ::int4 rwm[4];
  {
    const ::int4* gwi = (const ::int4*)wi4;  // 16 int4 per row
#pragma unroll
    for (int m = 0; m < 4; ++m) rwm[m] = gwi[grow * 16 + q * 4 + m];
  }
  const float sr = __fmul_rn(__fdiv_rn(S_res[grow], 49.0f), g_res[0]);
  const float si = __fmul_rn(__fdiv_rn(S_in[grow], 21.0f), g_in[0]);

  const unsigned lds_wb = (unsigned)(size_t)smem + (unsigned)tid * 16u;

  // prologue: flags, u_t0 staging, u_{t0+1} prefetch
  if (tid < 8) lds_flag[tid] = -1;
  unsigned ureg = 0;
  if (tid < 128) {
    unsigned v0 = (tid < 64) ? (unsigned)um[(b * T_ + t0) * 64 + tid]
                             : (unsigned)ua[(b * T_ + t0) * 64 + (tid - 64)];
    lds_u[(t0 & 1) * 128 + tid] = (int)v0;
    if (t0 + 1 < T_)
      ureg = (tid < 64) ? (unsigned)um[(b * T_ + t0 + 1) * 64 + tid]
                        : (unsigned)ua[(b * T_ + t0 + 1) * 64 + (tid - 64)];
  }
  __syncthreads();  // once, outside the loop

  for (int t = t0; t < t1; ++t) {
    const int cbuf = t & 1, nbuf = cbuf ^ 1;
    // 1. stage u_{t+1} into opposite buffer (flag-chain makes this safe)
    if (t + 1 < t1 && tid < 128) lds_u[nbuf * 128 + tid] = (int)ureg;

    // 2. issue this thread's poll load (1 unit/thread, checked in step 5)
    const ull* pp = hq + (size_t)(cbuf * 16 + b) * 256 + tid;
    ull uv = xld(pp);

    // 3. issue the 16 weight ds_read_b128 (drain during the wait)
    i4v wreg[16];
    WLD(0, "0");      WLD(1, "4096");   WLD(2, "8192");   WLD(3, "12288");
    WLD(4, "16384");  WLD(5, "20480");  WLD(6, "24576");  WLD(7, "28672");
    WLD(8, "32768");  WLD(9, "36864");  WLD(10, "40960"); WLD(11, "45056");
    WLD(12, "49152"); WLD(13, "53248"); WLD(14, "57344"); WLD(15, "61440");

    // 4. input dot from lds_u[cbuf] (independent of h; fills the wait)
    int am = 0, aa = 0;
    {
      const ::int4* lu = (const ::int4*)(lds_u + cbuf * 128);
#pragma unroll
      for (int m = 0; m < 4; ++m) {
        ::int4 w = rwm[m];
        ::int4 uM = lu[q * 4 + m];
        ::int4 uA = lu[16 + q * 4 + m];
        am = sdot8(w.x, uM.x, am); am = sdot8(w.y, uM.y, am);
        am = sdot8(w.z, uM.z, am); am = sdot8(w.w, uM.w, am);
        aa = sdot8(w.x, uA.x, aa); aa = sdot8(w.y, uA.y, aa);
        aa = sdot8(w.z, uA.z, aa); aa = sdot8(w.w, uA.w, aa);
      }
    }
    int accin = am + (aa << 3);
    accin += __shfl_xor(accin, 1);
    accin += __shfl_xor(accin, 2);

    // 5. poll check/retry (per-lane; wave proceeds when all 64 units seen)
    {
      const unsigned tg = (unsigned)t;
      int fails = 0;
      while ((unsigned)(uv >> 32) != tg) {
        if (++fails > 1) __builtin_amdgcn_s_sleep(1);
        uv = xld(pp);
      }
    }
    // 6. stage own unit (wave wv covers quarter wv) + release flag
    lds_h[cbuf * 272 + wv * 68 + lane] = (int)uv;
    if (lane == 0)
      __hip_atomic_store(&lds_flag[cbuf * 4 + wv], t, __ATOMIC_RELEASE,
                         __HIP_MEMORY_SCOPE_WORKGROUP);
    asm volatile("s_waitcnt lgkmcnt(0)" ::: "memory");  // weights + data fenced
    __builtin_amdgcn_sched_barrier(0);

    // 7. flag-gated quarter dots: early arrivals overlap late L3 latency
    int c0 = 0, c1 = 0, c2 = 0, c3 = 0;
    const int* hbase = lds_h + cbuf * 272;
    QDOT(0) QDOT(1) QDOT(2) QDOT(3)
    int acc = (c0 + c1) + (c2 + c3);
    acc += __shfl_xor(acc, 1);
    acc += __shfl_xor(acc, 2);

    // 8. exact int16 saturation, scales, reference tanh, requantize
    int cr = min(max(acc, -32768), 32767);
    int ci = min(max(accin, -32768), 32767);
    float arg = __fadd_rn(__fmul_rn((float)cr, sr), __fmul_rn((float)ci, si));
    float hn = tanh_ref(arg);
    float hc = fminf(fmaxf(hn, -1.0f), 1.0f);
    int qv = (int)rintf(__fmul_rn(hc, 7.0f));

    // 9. pack 8 rows -> 1 dword per 32-lane half; publish ASAP
    unsigned nib = ((unsigned)qv & 15u) << (4 * ((lane >> 2) & 7));
    nib |= (unsigned)__shfl_xor((int)nib, 4);
    nib |= (unsigned)__shfl_xor((int)nib, 8);
    nib |= (unsigned)__shfl_xor((int)nib, 16);
    if ((lane & 31) == 0)
      publish_tag(hq + (size_t)(nbuf * 16 + b) * 256 + slice * 8 + wv * 2 + (lane >> 5),
                  nib, (unsigned)(t + 1));

    // 10. bf16 h history (pair rows) + next-u prefetch (off critical path)
    unsigned bfb = f2bf(hn);
    unsigned other = (unsigned)__shfl_xor((int)bfb, 4);
    if ((tid & 7) == 0)
      Hs[(size_t)(b * T_ + t) * (H_ / 2) + slice * 32 + (tid >> 3)] = bfb | (other << 16);
    if (t + 2 < T_ && tid < 128)
      ureg = (tid < 64) ? (unsigned)um[(b * T_ + t + 2) * 64 + tid]
                        : (unsigned)ua[(b * T_ + t + 2) * 64 + (tid - 64)];
  }
}

// ---- deferred readout: 512 blocks x 256 thr; 16 bt-rows x 64 v per block ---
#define ACC8(acc, p, w0, w1)                                    \
  acc = fmaf(__uint_as_float(p.x << 16), w0.x, acc);            \
  acc = fmaf(__uint_as_float(p.x & 0xffff0000u), w0.y, acc);    \
  acc = fmaf(__uint_as_float(p.y << 16), w0.z, acc);            \
  acc = fmaf(__uint_as_float(p.y & 0xffff0000u), w0.w, acc);    \
  acc = fmaf(__uint_as_float(p.z << 16), w1.x, acc);            \
  acc = fmaf(__uint_as_float(p.z & 0xffff0000u), w1.y, acc);    \
  acc = fmaf(__uint_as_float(p.w << 16), w1.z, acc);            \
  acc = fmaf(__uint_as_float(p.w & 0xffff0000u), w1.w, acc);

__global__ void __launch_bounds__(256) readout(const unsigned* __restrict__ Hs,
                                               const float* __restrict__ Wout,
                                               const float* __restrict__ Wb,
                                               float* __restrict__ out) {
  const int v = threadIdx.x & 63;
  const int rg = threadIdx.x >> 6;              // 0..3
  const int bt0 = blockIdx.x * 16 + rg * 4;     // 4 consecutive bt rows
  const float* wrow = Wout + (size_t)v * H_;
  const unsigned* h0 = Hs + (size_t)bt0 * (H_ / 2);
  float a0 = Wb[v], a1 = a0, a2 = a0, a3 = a0;
  for (int j = 0; j < H_ / 2; j += 4) {
    float4 w0 = *(const float4*)(wrow + 2 * j);
    float4 w1 = *(const float4*)(wrow + 2 * j + 4);
    uint4 p0 = *(const uint4*)(h0 + j);
    uint4 p1 = *(const uint4*)(h0 + (H_ / 2) + j);
    uint4 p2 = *(const uint4*)(h0 + 2 * (H_ / 2) + j);
    uint4 p3 = *(const uint4*)(h0 + 3 * (H_ / 2) + j);
    ACC8(a0, p0, w0, w1)
    ACC8(a1, p1, w0, w1)
    ACC8(a2, p2, w0, w1)
    ACC8(a3, p3, w0, w1)
  }
  out[(size_t)(bt0 + 0) * V_ + v] = a0;
  out[(size_t)(bt0 + 1) * V_ + v] = a1;
  out[(size_t)(bt0 + 2) * V_ + v] = a2;
  out[(size_t)(bt0 + 3) * V_ + v] = a3;
}

extern "C" void kernel_launch(void* const* d_in, const int* in_sizes, int n_in,
                              void* d_out, int out_size, void* d_ws, size_t ws_size,
                              hipStream_t stream) {
  const float* x = (const float*)d_in[0];
  const float* S_res = (const float*)d_in[1];
  const float* S_in = (const float*)d_in[2];
  const float* g_res = (const float*)d_in[3];
  const float* g_in = (const float*)d_in[4];
  const float* Woutw = (const float*)d_in[5];
  const float* Woutb = (const float*)d_in[6];
  const int* Wres = (const int*)d_in[7];
  const int* Win = (const int*)d_in[8];

  char* ws = (char*)d_ws;
  ull* hq = (ull*)(ws + 4096);                  // 64 KiB tagged h units
  int* um = (int*)(ws + (1 << 20));             // 2 MiB
  int* ua = um + (1 << 19);                     // 2 MiB
  int* wr4 = ua + (1 << 19);                    // 2 MiB
  int* wi4 = wr4 + (1 << 19);                   // 512 KiB
  unsigned* Hs = (unsigned*)(ws + (8 << 20));   // 32 MiB bf16 h history

  hipMemsetAsync(ws + 4096, 0, 65536, stream);  // hq: h0 = 0, tag0 = 0
  hipLaunchKernelGGL(pack_weights, dim3(2560), dim3(256), 0, stream, Wres, Win, wr4, wi4);
  hipLaunchKernelGGL(pack_u, dim3(2048), dim3(256), 0, stream, x, um, ua);

  const int smem_bytes = 65536 + 2 * 272 * 4 + 2 * 128 * 4 + 8 * 4;  // 68768
  (void)hipFuncSetAttribute((const void*)esn_main, hipFuncAttributeMaxDynamicSharedMemorySize,
                            smem_bytes);

  int t0 = 0, t1 = T_;
  void* args[] = {&um, &ua, &wr4, &wi4, &hq, &S_res, &S_in,
                  &g_res, &g_in, &Hs, &t0, &t1};
  hipError_t e = hipLaunchCooperativeKernel((const void*)esn_main, dim3(NWG), dim3(NTHREADS),
                                            args, smem_bytes, stream);
  if (e != hipSuccess) {
    // fallback: one launch per timestep (kernel boundary = sync)
    for (int t = 0; t < T_; ++t) {
      hipLaunchKernelGGL(esn_main, dim3(NWG), dim3(NTHREADS), smem_bytes, stream,
                         um, ua, wr4, wi4, hq, S_res, S_in, g_res, g_in, Hs, t, t + 1);
    }
  }
  hipLaunchKernelGGL(readout, dim3(B_ * T_ / 16), dim3(256), 0, stream,
                     Hs, Woutw, Woutb, (float*)d_out);
}